// Round 2
// baseline (858.941 us; speedup 1.0000x reference)
//
#include <hip/hip_runtime.h>

#define B_ 128
#define T_ 128
#define I_ 1024
#define O_ 1024
#define M_ (B_*T_)          // 16384 rows of h
#define NOUT (M_*O_)        // 16777216 spike outputs, loss at index NOUT

// ---------------------------------------------------------------------------
// h = x @ w   (A: [M,K] row-major, B: [K,N] row-major, C: [M,N])
// 128x128 block tile, 256 threads, 8x8 micro-tile, double-buffered LDS:
// prefetch tile t+1 (global->regs) overlaps compute on tile t; the vmcnt
// wait lands at the LDS-write after compute. One barrier per K-tile.
// ---------------------------------------------------------------------------
__global__ __launch_bounds__(256) void gemm_xw(const float* __restrict__ A,
                                               const float* __restrict__ Bw,
                                               float* __restrict__ C) {
    const int K = I_, N = O_;
    __shared__ float As[2][16][132];   // transposed A tile, padded
    __shared__ float Bs[2][16][128];

    const int tid = threadIdx.x;
    const int tx = tid & 15, ty = tid >> 4;
    const int bm = blockIdx.x * 128, bn = blockIdx.y * 128;

    const int ar = tid >> 2;          // 0..63
    const int ac = (tid & 3) << 2;    // 0,4,8,12
    const int br = tid >> 5;          // 0..7
    const int bc = (tid & 31) << 2;   // 0..124

    const float* Aptr0 = A + (size_t)(bm + ar) * K + ac;
    const float* Aptr1 = A + (size_t)(bm + ar + 64) * K + ac;
    const float* Bptr0 = Bw + (size_t)br * N + bn + bc;
    const float* Bptr1 = Bw + (size_t)(br + 8) * N + bn + bc;

    float acc[2][2][4][4];
#pragma unroll
    for (int i = 0; i < 2; i++)
#pragma unroll
        for (int j = 0; j < 2; j++)
#pragma unroll
            for (int m = 0; m < 4; m++)
#pragma unroll
                for (int n = 0; n < 4; n++) acc[i][j][m][n] = 0.f;

    // tile 0 load + stage
    float4 a0 = *(const float4*)(Aptr0);
    float4 a1 = *(const float4*)(Aptr1);
    float4 b0 = *(const float4*)(Bptr0);
    float4 b1 = *(const float4*)(Bptr1);
    As[0][ac + 0][ar] = a0.x; As[0][ac + 1][ar] = a0.y;
    As[0][ac + 2][ar] = a0.z; As[0][ac + 3][ar] = a0.w;
    As[0][ac + 0][ar + 64] = a1.x; As[0][ac + 1][ar + 64] = a1.y;
    As[0][ac + 2][ar + 64] = a1.z; As[0][ac + 3][ar + 64] = a1.w;
    *(float4*)&Bs[0][br][bc] = b0;
    *(float4*)&Bs[0][br + 8][bc] = b1;
    __syncthreads();

    const int nt = K / 16;
    for (int t = 0; t < nt; ++t) {
        const int cur = t & 1, nxt = cur ^ 1;
        if (t + 1 < nt) {
            const int k0 = (t + 1) * 16;
            a0 = *(const float4*)(Aptr0 + k0);
            a1 = *(const float4*)(Aptr1 + k0);
            b0 = *(const float4*)(Bptr0 + (size_t)k0 * N);
            b1 = *(const float4*)(Bptr1 + (size_t)k0 * N);
        }
#pragma unroll
        for (int k = 0; k < 16; ++k) {
            float4 av0 = *(const float4*)&As[cur][k][ty * 4];
            float4 av1 = *(const float4*)&As[cur][k][64 + ty * 4];
            float4 bv0 = *(const float4*)&Bs[cur][k][tx * 4];
            float4 bv1 = *(const float4*)&Bs[cur][k][64 + tx * 4];
            float am[2][4] = {{av0.x, av0.y, av0.z, av0.w},
                              {av1.x, av1.y, av1.z, av1.w}};
            float bb[2][4] = {{bv0.x, bv0.y, bv0.z, bv0.w},
                              {bv1.x, bv1.y, bv1.z, bv1.w}};
#pragma unroll
            for (int mi = 0; mi < 2; mi++)
#pragma unroll
                for (int ni = 0; ni < 2; ni++)
#pragma unroll
                    for (int mm = 0; mm < 4; mm++)
#pragma unroll
                        for (int nn = 0; nn < 4; nn++)
                            acc[mi][ni][mm][nn] += am[mi][mm] * bb[ni][nn];
        }
        if (t + 1 < nt) {
            As[nxt][ac + 0][ar] = a0.x; As[nxt][ac + 1][ar] = a0.y;
            As[nxt][ac + 2][ar] = a0.z; As[nxt][ac + 3][ar] = a0.w;
            As[nxt][ac + 0][ar + 64] = a1.x; As[nxt][ac + 1][ar + 64] = a1.y;
            As[nxt][ac + 2][ar + 64] = a1.z; As[nxt][ac + 3][ar + 64] = a1.w;
            *(float4*)&Bs[nxt][br][bc] = b0;
            *(float4*)&Bs[nxt][br + 8][bc] = b1;
            __syncthreads();
        }
    }
#pragma unroll
    for (int mi = 0; mi < 2; mi++)
#pragma unroll
        for (int mm = 0; mm < 4; mm++) {
            int m = bm + mi * 64 + ty * 4 + mm;
#pragma unroll
            for (int ni = 0; ni < 2; ni++) {
                float4 v = make_float4(acc[mi][ni][mm][0], acc[mi][ni][mm][1],
                                       acc[mi][ni][mm][2], acc[mi][ni][mm][3]);
                *(float4*)(C + (size_t)m * N + bn + ni * 64 + tx * 4) = v;
            }
        }
}

// ---------------------------------------------------------------------------
// d = w^T w   (w: [K=I_, N=O_] row-major). 64x64 tile, KT=32, 256 threads.
// ---------------------------------------------------------------------------
__global__ __launch_bounds__(256) void gemm_wtw(const float* __restrict__ W,
                                                float* __restrict__ D) {
    const int K = I_, N = O_;
    __shared__ float As[32][68];
    __shared__ float Bs[32][68];
    const int tid = threadIdx.x;
    const int tx = tid & 15, ty = tid >> 4;
    const int bj = blockIdx.x * 64, bo = blockIdx.y * 64;
    const int lr = tid >> 4;          // 0..15
    const int lc = (tid & 15) << 2;   // 0..60

    float acc[4][4];
#pragma unroll
    for (int m = 0; m < 4; m++)
#pragma unroll
        for (int n = 0; n < 4; n++) acc[m][n] = 0.f;

    for (int k0 = 0; k0 < K; k0 += 32) {
        float4 a0 = *(const float4*)(W + (size_t)(k0 + lr) * N + bj + lc);
        float4 a1 = *(const float4*)(W + (size_t)(k0 + lr + 16) * N + bj + lc);
        float4 b0 = *(const float4*)(W + (size_t)(k0 + lr) * N + bo + lc);
        float4 b1 = *(const float4*)(W + (size_t)(k0 + lr + 16) * N + bo + lc);
        __syncthreads();
        *(float4*)&As[lr][lc] = a0; *(float4*)&As[lr + 16][lc] = a1;
        *(float4*)&Bs[lr][lc] = b0; *(float4*)&Bs[lr + 16][lc] = b1;
        __syncthreads();
#pragma unroll
        for (int k = 0; k < 32; ++k) {
            float4 av = *(const float4*)&As[k][ty * 4];
            float4 bv = *(const float4*)&Bs[k][tx * 4];
            float am[4] = {av.x, av.y, av.z, av.w};
            float bb[4] = {bv.x, bv.y, bv.z, bv.w};
#pragma unroll
            for (int m = 0; m < 4; m++)
#pragma unroll
                for (int n = 0; n < 4; n++) acc[m][n] += am[m] * bb[n];
        }
    }
#pragma unroll
    for (int m = 0; m < 4; m++) {
        float4 v = make_float4(acc[m][0], acc[m][1], acc[m][2], acc[m][3]);
        *(float4*)(D + (size_t)(bj + ty * 4 + m) * N + bo + tx * 4) = v;
    }
}

// ---------------------------------------------------------------------------
// inv_norm[o] = 1 / (sum_c w[c][o]^2 + 1e-8); also zero the spike counter.
// ---------------------------------------------------------------------------
__global__ void colnorm(const float* __restrict__ W, float* __restrict__ invn,
                        unsigned int* __restrict__ counter) {
    int o = blockIdx.x * 256 + threadIdx.x;
    if (o == 0) *counter = 0u;
    float s = 0.f;
    for (int c = 0; c < I_; ++c) {
        float v = W[(size_t)c * O_ + o];
        s += v * v;
    }
    invn[o] = 1.0f / (s + 1e-8f);
}

// ---------------------------------------------------------------------------
// Sequential scan: one block per batch sample; thread owns 4 CONTIGUOUS
// neurons so each gathered d-row is one dwordx4. Gather batched 4 rows at a
// time (4 outstanding b128 loads per wait). h(t+1) prefetched before the
// gather so HBM latency overlaps it.
// ---------------------------------------------------------------------------
__global__ __launch_bounds__(256) void scan_kernel(const float* __restrict__ h,
                                                   const float* __restrict__ d,
                                                   const float* __restrict__ invn,
                                                   const float* __restrict__ bias,
                                                   const float* __restrict__ beta,
                                                   float* __restrict__ out,
                                                   unsigned int* __restrict__ spike_count) {
    __shared__ int lst[2][O_];
    __shared__ int cnt[2];
    __shared__ unsigned int red[256];

    const int tid = threadIdx.x;
    const int b = blockIdx.x;
    const int o4 = tid * 4;
    const float betav = beta[0];
    const float omb = 1.0f - betav;

    const float4 invn4 = *(const float4*)(invn + o4);
    const float4 b4 = *(const float4*)(bias + o4);
    float4 mem4 = make_float4(0.f, 0.f, 0.f, 0.f);

    if (tid < 2) cnt[tid] = 0;
    unsigned int local_count = 0;
    const float* hb = h + (size_t)b * T_ * O_;
    float* ob = out + (size_t)b * T_ * O_;

    float4 hcur = *(const float4*)(hb + o4);   // t = 0
    __syncthreads();

    for (int t = 0; t < T_; ++t) {
        const int p = t & 1, q = p ^ 1;
        const int n = cnt[p];
        __syncthreads();                 // everyone has read n
        if (tid == 0) cnt[p] = 0;        // ready for appends at step t+2

        // prefetch h for t+1 (latency hidden behind the gather)
        float4 hnext = make_float4(0.f, 0.f, 0.f, 0.f);
        if (t + 1 < T_) hnext = *(const float4*)(hb + (size_t)(t + 1) * O_ + o4);

        float4 rst = make_float4(0.f, 0.f, 0.f, 0.f);
        int i = 0;
        for (; i + 4 <= n; i += 4) {
            const int j0 = lst[p][i + 0];
            const int j1 = lst[p][i + 1];
            const int j2 = lst[p][i + 2];
            const int j3 = lst[p][i + 3];
            float4 v0 = *(const float4*)(d + (size_t)j0 * O_ + o4);
            float4 v1 = *(const float4*)(d + (size_t)j1 * O_ + o4);
            float4 v2 = *(const float4*)(d + (size_t)j2 * O_ + o4);
            float4 v3 = *(const float4*)(d + (size_t)j3 * O_ + o4);
            rst.x += (v0.x + v1.x) + (v2.x + v3.x);
            rst.y += (v0.y + v1.y) + (v2.y + v3.y);
            rst.z += (v0.z + v1.z) + (v2.z + v3.z);
            rst.w += (v0.w + v1.w) + (v2.w + v3.w);
        }
        for (; i < n; ++i) {
            const int j = lst[p][i];
            float4 v = *(const float4*)(d + (size_t)j * O_ + o4);
            rst.x += v.x; rst.y += v.y; rst.z += v.z; rst.w += v.w;
        }

        mem4.x = (mem4.x - rst.x) * betav + hcur.x * omb;
        mem4.y = (mem4.y - rst.y) * betav + hcur.y * omb;
        mem4.z = (mem4.z - rst.z) * betav + hcur.z * omb;
        mem4.w = (mem4.w - rst.w) * betav + hcur.w * omb;

        const int s0 = (mem4.x * invn4.x - b4.x) > 0.0f;
        const int s1 = (mem4.y * invn4.y - b4.y) > 0.0f;
        const int s2 = (mem4.z * invn4.z - b4.z) > 0.0f;
        const int s3 = (mem4.w * invn4.w - b4.w) > 0.0f;

        float4 sv = make_float4(s0 ? 1.f : 0.f, s1 ? 1.f : 0.f,
                                s2 ? 1.f : 0.f, s3 ? 1.f : 0.f);
        *(float4*)(ob + (size_t)t * O_ + o4) = sv;
        local_count += (unsigned)(s0 + s1 + s2 + s3);

        if (s0) { int pos = atomicAdd(&cnt[q], 1); lst[q][pos] = o4 + 0; }
        if (s1) { int pos = atomicAdd(&cnt[q], 1); lst[q][pos] = o4 + 1; }
        if (s2) { int pos = atomicAdd(&cnt[q], 1); lst[q][pos] = o4 + 2; }
        if (s3) { int pos = atomicAdd(&cnt[q], 1); lst[q][pos] = o4 + 3; }

        __syncthreads();                 // appends visible for next gather
        hcur = hnext;
    }

    // block reduction of spike count
    red[tid] = local_count;
    __syncthreads();
    for (int s = 128; s > 0; s >>= 1) {
        if (tid < s) red[tid] += red[tid + s];
        __syncthreads();
    }
    if (tid == 0) atomicAdd(spike_count, red[0]);
}

__global__ void finalize_loss(const unsigned int* __restrict__ spike_count,
                              float* __restrict__ loss_out) {
    // count <= 2^24 so float is exact; /2^24 and *0.5 are exact scalings
    *loss_out = 0.5f * ((float)(*spike_count) / 16777216.0f);
}

// ---------------------------------------------------------------------------
extern "C" void kernel_launch(void* const* d_in, const int* in_sizes, int n_in,
                              void* d_out, int out_size, void* d_ws, size_t ws_size,
                              hipStream_t stream) {
    const float* x    = (const float*)d_in[0];   // [B,T,I]
    const float* w    = (const float*)d_in[1];   // [I,O]
    const float* beta = (const float*)d_in[2];   // [1]
    const float* bias = (const float*)d_in[3];   // [O]
    float* out = (float*)d_out;                  // NOUT spikes + 1 loss

    // workspace layout
    char* ws = (char*)d_ws;
    float* h    = (float*)ws;                                   // 64 MiB
    float* dmat = (float*)(ws + (size_t)67108864);              // 4 MiB
    float* invn = (float*)(ws + (size_t)67108864 + 4194304);    // 4 KiB
    unsigned int* cntp = (unsigned int*)(ws + (size_t)67108864 + 4194304 + 4096);

    gemm_xw<<<dim3(M_ / 128, O_ / 128), 256, 0, stream>>>(x, w, h);
    gemm_wtw<<<dim3(O_ / 64, O_ / 64), 256, 0, stream>>>(w, dmat);
    colnorm<<<O_ / 256, 256, 0, stream>>>(w, invn, cntp);
    scan_kernel<<<B_, 256, 0, stream>>>(h, dmat, invn, bias, beta, out, cntp);
    finalize_loss<<<1, 1, 0, stream>>>(cntp, out + (size_t)NOUT);
}